// Round 9
// baseline (205.396 us; speedup 1.0000x reference)
//
#include <hip/hip_runtime.h>
#include <stdint.h>

typedef unsigned short u16;
typedef unsigned int   u32;
typedef __attribute__((ext_vector_type(8))) short bf16x8;  // 8 bf16 = 4 VGPR
typedef __attribute__((ext_vector_type(4))) short bf16x4;  // 4 bf16 = 2 VGPR
typedef __attribute__((ext_vector_type(4))) float f32x4;   // MFMA C/D frag
typedef __attribute__((ext_vector_type(16))) float f32x16; // 32x32 MFMA C/D frag

#define NT ((size_t)8388608)   // 32*1024*256 elements

// ---------- helpers ----------
__device__ __forceinline__ float bf2f(u16 u) {
  union { float f; u32 i; } v; v.i = ((u32)u) << 16; return v.f;
}
__device__ __forceinline__ u16 f2bf(float f) {
  union { float f; u32 i; } v; v.f = f;
  u32 r = (v.i + 0x7fffu + ((v.i >> 16) & 1u)) >> 16;   // RNE
  return (u16)r;
}
__device__ __forceinline__ u32 fbits(float f) {
  union { float f; u32 i; } v; v.f = f; return v.i;
}
// bf16-vs-f32 buffer sniff (64-lane ballot on exponent-byte position)
__device__ __forceinline__ int detect_bf16(const u32* __restrict__ xd) {
  u32 w = xd[threadIdx.x & 63];
  u32 e = (w >> 8) & 0x7fu;
  unsigned long long m = __ballot((e >= 0x38u) && (e <= 0x41u));
  return __popcll(m) > 32;
}
// async 16B/lane global->LDS (dest = wave-uniform base + lane*16)
__device__ __forceinline__ void gld16(const void* g, void* l) {
  __builtin_amdgcn_global_load_lds((const __attribute__((address_space(1))) u32*)g,
                                   (__attribute__((address_space(3))) u32*)l, 16, 0, 0);
}

// ---------- prologue (reduced): Wq/Wk/Wv prep (0..191) + optional Wo (192..255) ----------
// The 2048-block x-transpose is GONE: qkv_gemm now reads x directly and
// transposes during LDS staging (saves a full 50MB pass + a kernel launch).
__global__ void __launch_bounds__(256) prologue_kernel(const void* __restrict__ xin,
                                                       const void* __restrict__ W0, const void* __restrict__ W1,
                                                       const void* __restrict__ W2, const void* __restrict__ b0,
                                                       const void* __restrict__ b1, const void* __restrict__ b2,
                                                       u16* __restrict__ wdst, float* __restrict__ bdst,
                                                       const void* __restrict__ Wo, const void* __restrict__ bo,
                                                       const void* __restrict__ gm, u16* __restrict__ wodst,
                                                       float* __restrict__ bodst) {
  const int blk = blockIdx.x;
  const int tid = threadIdx.x;
  const int isbf = detect_bf16((const u32*)xin);
  if (blk < 192) {
    const int which = blk >> 6, bk = blk & 63;
    const void* Ws = which == 0 ? W0 : which == 1 ? W1 : W2;
    const void* bs = which == 0 ? b0 : which == 1 ? b1 : b2;
    const int idx = bk * 1024 + tid * 4;
    u16* dst = wdst + which * 65536 + idx;
    if (isbf) {
      *(ushort4*)dst = *(const ushort4*)((const u16*)Ws + idx);
    } else {
      const float4 sv = *(const float4*)((const float*)Ws + idx);
      ushort4 o; o.x = f2bf(sv.x); o.y = f2bf(sv.y); o.z = f2bf(sv.z); o.w = f2bf(sv.w);
      *(ushort4*)dst = o;
    }
    if (bk == 0) {
      bdst[which * 256 + tid] = isbf ? bf2f(((const u16*)bs)[tid]) : ((const float*)bs)[tid];
    }
  } else {
    const int g = blk - 192;             // 64 blocks: Wo
    const int idx = g * 1024 + tid * 4;
    if (isbf) {
      *(ushort4*)(wodst + idx) = *(const ushort4*)((const u16*)Wo + idx);
    } else {
      const float4 sv = *(const float4*)((const float*)Wo + idx);
      ushort4 o; o.x = f2bf(sv.x); o.y = f2bf(sv.y); o.z = f2bf(sv.z); o.w = f2bf(sv.w);
      *(ushort4*)(wodst + idx) = o;
    }
    if (g == 0) {
      bodst[tid] = isbf ? bf2f(((const u16*)bo)[tid]) : ((const float*)bo)[tid];
      if (tid == 0) bodst[256] = isbf ? bf2f(((const u16*)gm)[0]) : ((const float*)gm)[0];
    }
  }
}

// ---------- Wo prep fallback (when ws tail unavailable; runs after attn) ----------
__global__ void __launch_bounds__(256) prep_o(const void* __restrict__ Wo, const void* __restrict__ bo,
                                              const void* __restrict__ gm, u16* __restrict__ wdst,
                                              float* __restrict__ bdst, const u32* __restrict__ xdet) {
  const int isbf = detect_bf16(xdet);
  const int idx = blockIdx.x * 1024 + threadIdx.x * 4;
  if (isbf) {
    *(ushort4*)(wdst + idx) = *(const ushort4*)((const u16*)Wo + idx);
  } else {
    const float4 sv = *(const float4*)((const float*)Wo + idx);
    ushort4 o; o.x = f2bf(sv.x); o.y = f2bf(sv.y); o.z = f2bf(sv.z); o.w = f2bf(sv.w);
    *(ushort4*)(wdst + idx) = o;
  }
  if (blockIdx.x == 0) {
    int t = threadIdx.x;
    bdst[t] = isbf ? bf2f(((const u16*)bo)[t]) : ((const float*)bo)[t];
    if (t == 0) bdst[256] = isbf ? bf2f(((const u16*)gm)[0]) : ((const float*)gm)[0];
  }
}

// ---------- fused QKV projection v2: reads x DIRECTLY, transposes in staging ----------
// D[m=c][n=s], A = W (gld16-staged, xor-swizzled as before), B = x^T built on
// the fly: per k0, thread (cp=t&31, sg=t>>5) loads 2 c-rows x 16 s (64B/row,
// coalesced), packs the c-pair into u32 (cvt_pk f32 path / v_perm bf16 path),
// writes Bsh32[s][cp] -- banks (4i+cp)%32, cp spans 0..31 => 2 lanes/bank
// (free). B-frag ds_read_b128 at pitch 144B: banks 4(s+g)%32 => 2-way (free).
__global__ void __launch_bounds__(256) qkv_gemm(const void* __restrict__ xin,
                                                const u16* __restrict__ Wall,
                                                const float* __restrict__ ball,
                                                u16* __restrict__ Qb, u16* __restrict__ Kb,
                                                u16* __restrict__ Vb) {
  const int z = blockIdx.z, b = z / 3, which = z - b * 3;
  const int tid = threadIdx.x, lane = tid & 63, wave = tid >> 6;
  const int quad = lane >> 4, l16 = lane & 15;
  const int wm = wave >> 1, wn = wave & 1;
  const int isbf = detect_bf16((const u32*)xin);
  const u16* W = Wall + which * 65536;
  const int m0 = blockIdx.y * 128;   // c tile (2)
  const int n0 = blockIdx.x * 128;   // s tile (8)

  __shared__ u16 Ash[8192];                        // W 128x64, xor-swizzled granules
  __shared__ __align__(16) u16 Bsh[128 * 72];      // x^T 128(s) x 64(c) + 8 pad
  u32* B32 = (u32*)Bsh;
  f32x4 acc[4][4];
#pragma unroll
  for (int i = 0; i < 4; i++)
#pragma unroll
    for (int j = 0; j < 4; j++) acc[i][j] = (f32x4){0.f, 0.f, 0.f, 0.f};

  const int srow = lane >> 3;
  const int sgc = (lane & 7) ^ (srow & 7);   // pre-swizzled source k-granule (A only)
  const int cp = tid & 31, sg = tid >> 5, si = sg * 16;

  for (int k0 = 0; k0 < 256; k0 += 64) {
    // issue B-tile global reads early (no LDS dependence)
    float fa[16], fb[16];
    uint4 ua[2], ub[2];
    if (isbf) {
      const u16* ra = (const u16*)xin + ((size_t)(b * 256 + k0 + 2 * cp)) * 1024 + n0 + si;
      ua[0] = *(const uint4*)ra; ua[1] = *(const uint4*)(ra + 8);
      ub[0] = *(const uint4*)(ra + 1024); ub[1] = *(const uint4*)(ra + 1032);
    } else {
      const float* ra = (const float*)xin + ((size_t)(b * 256 + k0 + 2 * cp)) * 1024 + n0 + si;
      const float* rb = ra + 1024;
#pragma unroll
      for (int q = 0; q < 4; q++) {
        const float4 va = ((const float4*)ra)[q];
        const float4 vc = ((const float4*)rb)[q];
        fa[q * 4 + 0] = va.x; fa[q * 4 + 1] = va.y; fa[q * 4 + 2] = va.z; fa[q * 4 + 3] = va.w;
        fb[q * 4 + 0] = vc.x; fb[q * 4 + 1] = vc.y; fb[q * 4 + 2] = vc.z; fb[q * 4 + 3] = vc.w;
      }
    }
    __syncthreads();   // WAR: prior frag reads done before restage lands
    if (isbf) {
      const u32* au = (const u32*)ua;   // au[j]: s=2j,2j+1 of row 2cp
      const u32* bu = (const u32*)ub;   // bu[j]: same s of row 2cp+1
#pragma unroll
      for (int j = 0; j < 8; j++) {
        const u32 lo = __builtin_amdgcn_perm(bu[j], au[j], 0x05040100u);
        const u32 hi = __builtin_amdgcn_perm(bu[j], au[j], 0x07060302u);
        B32[(si + 2 * j) * 36 + cp] = lo;
        B32[(si + 2 * j + 1) * 36 + cp] = hi;
      }
    } else {
#pragma unroll
      for (int i = 0; i < 16; i++) {
        u32 w;   // {bf16(rowA) lo, bf16(rowB) hi} = c-pair at column cp
        asm("v_cvt_pk_bf16_f32 %0, %1, %2" : "=v"(w) : "v"(fa[i]), "v"(fb[i]));
        B32[(si + i) * 36 + cp] = w;
      }
    }
#pragma unroll
    for (int p = 0; p < 4; p++) {
      const int row = p * 32 + wave * 8;
      gld16(W + (size_t)(m0 + row + srow) * 256 + k0 + sgc * 8, &Ash[row * 64 + lane * 8]);
    }
    __syncthreads();   // drains lgkm (ds_write) + vmcnt (gld16)
#pragma unroll
    for (int kk = 0; kk < 2; kk++) {
      bf16x8 av[4], bv[4];
      const int rg = (kk * 4 + quad) ^ (l16 & 7);   // A swizzled read granule
#pragma unroll
      for (int i = 0; i < 4; i++) av[i] = *(const bf16x8*)&Ash[(wm * 64 + i * 16 + l16) * 64 + rg * 8];
#pragma unroll
      for (int j = 0; j < 4; j++) bv[j] = *(const bf16x8*)&Bsh[(wn * 64 + j * 16 + l16) * 72 + kk * 32 + quad * 8];
#pragma unroll
      for (int i = 0; i < 4; i++)
#pragma unroll
        for (int j = 0; j < 4; j++)
          acc[i][j] = __builtin_amdgcn_mfma_f32_16x16x32_bf16(av[i], bv[j], acc[i][j], 0, 0, 0);
    }
  }

  const float* bias = ball + which * 256;
  const float scale = (which == 0) ? 0.25503486f : 1.0f;  // (1/sqrt(32))*log2(e) folded into Q
#pragma unroll
  for (int i = 0; i < 4; i++) {
#pragma unroll
    for (int j = 0; j < 4; j++) {
      const int mb = m0 + wm * 64 + i * 16 + quad * 4;   // c, 4-consecutive via r
      const int n = n0 + wn * 64 + j * 16 + l16;         // s
      if (which < 2) {
        u16* D = (which ? Kb : Qb) + (size_t)b * 262144;
        ushort4 st;
        st.x = f2bf((acc[i][j][0] + bias[mb + 0]) * scale);
        st.y = f2bf((acc[i][j][1] + bias[mb + 1]) * scale);
        st.z = f2bf((acc[i][j][2] + bias[mb + 2]) * scale);
        st.w = f2bf((acc[i][j][3] + bias[mb + 3]) * scale);
        // head-packed (h, s, dh); mb%4==0 so the quad stays inside one head
        *(ushort4*)(D + (size_t)(mb >> 5) * 32768 + (size_t)n * 32 + (mb & 31)) = st;
      } else {
        u16* D = Vb + (size_t)b * 262144;
#pragma unroll
        for (int r = 0; r < 4; r++) {
          const int m = mb + r;
          D[(size_t)m * 1024 + n] = f2bf(acc[i][j][r] + bias[m]);
        }
      }
    }
  }
}

// ---------- fused attention (best measured: 53.1us, unchanged) ----------
__global__ void __launch_bounds__(512) attn_kernel(const u16* __restrict__ Q,
                                                   const u16* __restrict__ K,
                                                   const u16* __restrict__ V,
                                                   u16* __restrict__ O) {
  const int blk = blockIdx.x;
  const int qc = blk >> 8, bh = blk & 255;
  const int b = bh >> 3, h = bh & 7;
  const int tid = threadIdx.x, wave = tid >> 6, lane = tid & 63;
  const int hi = lane >> 5, l32 = lane & 31;
  __shared__ __align__(16) u16 Ksh[2][128 * 32];  // [t][d] granule-swizzled
  __shared__ __align__(16) u16 Vsh[2][32 * 128];  // [d][t] granule col ^= (d&15)
  const u16* Qg = Q + (size_t)b * 262144 + (size_t)h * 32768;  // (b,h,s,32)
  const u16* Kg = K + (size_t)b * 262144 + (size_t)h * 32768;  // (b,h,s,32)
  const u16* Vg = V + (size_t)b * 262144 + (size_t)h * 32768;  // (b,h,dh,s)
  const int qw = qc * 256 + wave * 32;   // this wave's 32 q rows

  // Q frags (B-operand): lane n=l32 holds Q[q=qw+l32][d = ks*16 + hi*8 + j]
  bf16x8 qf[2];
#pragma unroll
  for (int ks = 0; ks < 2; ks++)
    qf[ks] = *(const bf16x8*)(Qg + (size_t)(qw + l32) * 32 + ks * 16 + hi * 8);

  // K staging: this lane's granule Gg; location Gg must hold K[t(Gg)][8*s(Gg)..+7]
  const int Gg = wave * 64 + lane;
  const int th = Gg >> 3;
  const int uu = (Gg & 7) ^ (th & 7);
  const u16* ksrc = Kg + (size_t)(th * 2 + (uu >> 2)) * 32 + (uu & 3) * 8;
  u16* kdst0 = &Ksh[0][Gg * 8];
  u16* kdst1 = &Ksh[1][Gg * 8];
  // V staging: granule tid holds V[d = tid>>4][8*((tid&15)^(d&15)) ..+7]
  const int vd = tid >> 4;
  const u16* vsrc = Vg + (size_t)vd * 1024 + ((tid & 15) ^ (vd & 15)) * 8;
  u16* vdst0 = &Vsh[0][tid * 8];
  u16* vdst1 = &Vsh[1][tid * 8];

  // kf read byte-offsets (A-operand, lane m = t = tt*32+l32, k-half ks): +tt*2048
  const int kkey = (l32 >> 1) & 7;
  const int kb0 = (l32 >> 1) * 128 + (((((l32 & 1) << 2) | 0 | hi) ^ kkey) << 4);
  const int kb1 = (l32 >> 1) * 128 + (((((l32 & 1) << 2) | 2 | hi) ^ kkey) << 4);
  // vf read byte-offsets: l32*256 + ((tg ^ (l32&15))<<4), tg = 4*tt + 2*m + hi
  int vb[4];
#pragma unroll
  for (int tt = 0; tt < 4; tt++) vb[tt] = l32 * 256 + (((l32 & 12) ^ (tt << 2)) << 4);
  const int vm0 = ((l32 & 3) ^ hi) << 4;
  const int vm1 = ((l32 & 3) ^ (2 | hi)) << 4;

  f32x16 oacc;
#pragma unroll
  for (int r = 0; r < 16; r++) oacc[r] = 0.f;
  f32x16 zro;   // persistent zero C-operand for QK^T (never written)
#pragma unroll
  for (int r = 0; r < 16; r++) zro[r] = 0.f;
  float lsum = 0.f;

  // prologue: stage tile 0
  gld16(ksrc, kdst0);
  gld16(vsrc, vdst0);
  __syncthreads();

#pragma unroll 1
  for (int kt = 0; kt < 8; kt++) {
    const int c = kt & 1;
    if (kt < 7) {   // issue next tile into the other buffer; drained at loop-end barrier
      gld16(ksrc + (size_t)(kt + 1) * 4096, c ? kdst0 : kdst1);   // 128 t-rows x 32
      gld16(vsrc + (kt + 1) * 128,          c ? vdst0 : vdst1);
    }
    const char* Kb = (const char*)&Ksh[c][0];
    const char* Vb = (const char*)&Vsh[c][0];
#pragma unroll
    for (int tt = 0; tt < 4; tt++) {
      const bf16x8 kf0 = *(const bf16x8*)(Kb + tt * 2048 + kb0);
      const bf16x8 kf1 = *(const bf16x8*)(Kb + tt * 2048 + kb1);
      const bf16x8 vf0 = *(const bf16x8*)(Vb + vb[tt] + vm0);
      const bf16x8 vf1 = *(const bf16x8*)(Vb + vb[tt] + vm1);
      __builtin_amdgcn_s_setprio(1);
      f32x16 sf = __builtin_amdgcn_mfma_f32_32x32x16_bf16(kf0, qf[0], zro, 0, 0, 0);
      sf = __builtin_amdgcn_mfma_f32_32x32x16_bf16(kf1, qf[1], sf, 0, 0, 0);
      __builtin_amdgcn_s_setprio(0);
      // ---- first 16 t of the tile (groups g0 = sf[0:3], g1 = sf[4:7]) ----
      {
        const float p0 = __builtin_amdgcn_exp2f(sf[0]);
        const float p1 = __builtin_amdgcn_exp2f(sf[1]);
        const float p2 = __builtin_amdgcn_exp2f(sf[2]);
        const float p3 = __builtin_amdgcn_exp2f(sf[3]);
        const float p4 = __builtin_amdgcn_exp2f(sf[4]);
        const float p5 = __builtin_amdgcn_exp2f(sf[5]);
        const float p6 = __builtin_amdgcn_exp2f(sf[6]);
        const float p7 = __builtin_amdgcn_exp2f(sf[7]);
        lsum += ((p0 + p1) + (p2 + p3)) + ((p4 + p5) + (p6 + p7));
        u32 wa, wb, wc, wd;
        asm("v_cvt_pk_bf16_f32 %0, %1, %2" : "=v"(wa) : "v"(p0), "v"(p1));
        asm("v_cvt_pk_bf16_f32 %0, %1, %2" : "=v"(wb) : "v"(p2), "v"(p3));
        asm("v_cvt_pk_bf16_f32 %0, %1, %2" : "=v"(wc) : "v"(p4), "v"(p5));
        asm("v_cvt_pk_bf16_f32 %0, %1, %2" : "=v"(wd) : "v"(p6), "v"(p7));
#if __has_builtin(__builtin_amdgcn_permlane32_swap)
        auto s0 = __builtin_amdgcn_permlane32_swap((int)wc, (int)wa, false, false);
        auto s1 = __builtin_amdgcn_permlane32_swap((int)wd, (int)wb, false, false);
        union { int w[4]; bf16x8 v; } pk;
        pk.w[0] = s0[1]; pk.w[1] = s1[1]; pk.w[2] = s0[0]; pk.w[3] = s1[0];
#else
        const u32 xa = __shfl_xor((int)wa, 32), xb = __shfl_xor((int)wb, 32);
        const u32 xc = __shfl_xor((int)wc, 32), xd = __shfl_xor((int)wd, 32);
        union { u32 w[4]; bf16x8 v; } pk;
        pk.w[0] = hi ? xc : wa; pk.w[1] = hi ? xd : wb;
        pk.w[2] = hi ? wc : xa; pk.w[3] = hi ? wd : xb;
#endif
        __builtin_amdgcn_s_setprio(1);
        oacc = __builtin_amdgcn_mfma_f32_32x32x16_bf16(pk.v, vf0, oacc, 0, 0, 0);
        __builtin_amdgcn_s_setprio(0);
      }
      // ---- second 16 t of the tile (groups g2 = sf[8:11], g3 = sf[12:15]) ----
      {
        const float p0 = __builtin_amdgcn_exp2f(sf[8]);
        const float p1 = __builtin_amdgcn_exp2f(sf[9]);
        const float p2 = __builtin_amdgcn_exp2f(sf[10]);
        const float p3 = __builtin_amdgcn_exp2f(sf[11]);
        const float p4 = __builtin_amdgcn_exp2f(sf[12]);
        const float p5 = __builtin_amdgcn_exp2f(sf[13]);
        const float p6 = __builtin_amdgcn_exp2f(sf[14]);
        const float p7 = __builtin_amdgcn_exp2f(sf[15]);
        lsum += ((p0 + p1) + (p2 + p3)) + ((p4 + p5) + (p6 + p7));
        u32 wa, wb, wc, wd;
        asm("v_cvt_pk_bf16_f32 %0, %1, %2" : "=v"(wa) : "v"(p0), "v"(p1));
        asm("v_cvt_pk_bf16_f32 %0, %1, %2" : "=v"(wb) : "v"(p2), "v"(p3));
        asm("v_cvt_pk_bf16_f32 %0, %1, %2" : "=v"(wc) : "v"(p4), "v"(p5));
        asm("v_cvt_pk_bf16_f32 %0, %1, %2" : "=v"(wd) : "v"(p6), "v"(p7));
#if __has_builtin(__builtin_amdgcn_permlane32_swap)
        auto s0 = __builtin_amdgcn_permlane32_swap((int)wc, (int)wa, false, false);
        auto s1 = __builtin_amdgcn_permlane32_swap((int)wd, (int)wb, false, false);
        union { int w[4]; bf16x8 v; } pk;
        pk.w[0] = s0[1]; pk.w[1] = s1[1]; pk.w[2] = s0[0]; pk.w[3] = s1[0];
#else
        const u32 xa = __shfl_xor((int)wa, 32), xb = __shfl_xor((int)wb, 32);
        const u32 xc = __shfl_xor((int)wc, 32), xd = __shfl_xor((int)wd, 32);
        union { u32 w[4]; bf16x8 v; } pk;
        pk.w[0] = hi ? xc : wa; pk.w[1] = hi ? xd : wb;
        pk.w[2] = hi ? wc : xa; pk.w[3] = hi ? wd : xb;
#endif
        __builtin_amdgcn_s_setprio(1);
        oacc = __builtin_amdgcn_mfma_f32_32x32x16_bf16(pk.v, vf1, oacc, 0, 0, 0);
        __builtin_amdgcn_s_setprio(0);
      }
    }
    if (kt < 7) __syncthreads();   // drains vmcnt (prefetch) + WAR for restage
  }

  // epilogue: row-sums (lane + its hi-partner), scale, store
  lsum += __shfl_xor(lsum, 32);
  const float linv = 1.0f / lsum;            // valid at lane for q = l32
  u16* Og = O + (size_t)(b * 1024 + qw) * 256 + h * 32 + l32;
#pragma unroll
  for (int r = 0; r < 16; r++) {
    const int qo = (r & 3) + 8 * (r >> 2) + 4 * hi;   // oacc row -> q offset
    const float li = __shfl(linv, qo);
    Og[(size_t)qo * 256] = f2bf(oacc[r] * li);
  }
}

// ---------- out projection + residual: out = 2x + g*(Wo.O + bo) ----------
// Orientation: D[m=s][n=c]; float4 x-loads and stores. Tiles 128(s) x 64(c).
__global__ void __launch_bounds__(256) out_gemm(const u16* __restrict__ WoB,
                                                const float* __restrict__ bg,
                                                const u16* __restrict__ Ob,
                                                const void* __restrict__ xin,
                                                void* __restrict__ outp,
                                                const u32* __restrict__ xdet) {
  const int b = blockIdx.z;
  const int m0 = blockIdx.x * 128;   // s tile (8)
  const int n0 = blockIdx.y * 64;    // c tile (4)
  const int tid = threadIdx.x, lane = tid & 63, wave = tid >> 6;
  const int quad = lane >> 4, l16 = lane & 15;
  const int wm = wave >> 1, wn = wave & 1;   // per wave: 64 m x 32 n
  const int isbf = detect_bf16(xdet);
  const u16* Ab = Ob + (size_t)b * 262144;   // A rows = s (k-major 256)
  __shared__ u16 Ash[8192], Bsh[4096];       // A 128x64, B 64x64 (swizzled granules)
  f32x4 acc[4][2];
#pragma unroll
  for (int i = 0; i < 4; i++)
#pragma unroll
    for (int j = 0; j < 2; j++) acc[i][j] = (f32x4){0.f, 0.f, 0.f, 0.f};

  const int srow = lane >> 3;
  const int sgc = (lane & 7) ^ (srow & 7);   // pre-swizzled source k-granule
  for (int k0 = 0; k0 < 256; k0 += 64) {
    __syncthreads();
#pragma unroll
    for (int p = 0; p < 4; p++) {
      const int row = p * 32 + wave * 8;
      gld16(Ab + (size_t)(m0 + row + srow) * 256 + k0 + sgc * 8, &Ash[row * 64 + lane * 8]);
    }
#pragma unroll
    for (int p = 0; p < 2; p++) {
      const int row = p * 32 + wave * 8;
      gld16(WoB + (size_t)(n0 + row + srow) * 256 + k0 + sgc * 8, &Bsh[row * 64 + lane * 8]);
    }
    __syncthreads();
#pragma unroll
    for (int kk = 0; kk < 2; kk++) {
      bf16x8 av[4], bv[2];
      const int rg = (kk * 4 + quad) ^ (l16 & 7);   // swizzled read granule
#pragma unroll
      for (int i = 0; i < 4; i++) av[i] = *(const bf16x8*)&Ash[(wm * 64 + i * 16 + l16) * 64 + rg * 8];
#pragma unroll
      for (int j = 0; j < 2; j++) bv[j] = *(const bf16x8*)&Bsh[(wn * 32 + j * 16 + l16) * 64 + rg * 8];
#pragma unroll
      for (int i = 0; i < 4; i++)
#pragma unroll
        for (int j = 0; j < 2; j++)
          acc[i][j] = __builtin_amdgcn_mfma_f32_16x16x32_bf16(av[i], bv[j], acc[i][j], 0, 0, 0);
    }
  }

  const float g = bg[256];
#pragma unroll
  for (int i = 0; i < 4; i++) {
#pragma unroll
    for (int j = 0; j < 2; j++) {
      const int mb = m0 + wm * 64 + i * 16 + quad * 4;   // s, 4-consecutive via r
      const int n = n0 + wn * 32 + j * 16 + l16;         // c
      const float bc = bg[n];
      const size_t gi = (size_t)b * 262144 + (size_t)n * 1024 + mb;
      if (isbf) {
        const ushort4 xv = *(const ushort4*)((const u16*)xin + gi);
        ushort4 st;
        st.x = f2bf(2.f * bf2f(xv.x) + g * (acc[i][j][0] + bc));
        st.y = f2bf(2.f * bf2f(xv.y) + g * (acc[i][j][1] + bc));
        st.z = f2bf(2.f * bf2f(xv.z) + g * (acc[i][j][2] + bc));
        st.w = f2bf(2.f * bf2f(xv.w) + g * (acc[i][j][3] + bc));
        *(ushort4*)((u16*)outp + gi) = st;
      } else {
        const float4 xv = *(const float4*)((const float*)xin + gi);
        float4 st;
        st.x = 2.f * xv.x + g * (acc[i][j][0] + bc);
        st.y = 2.f * xv.y + g * (acc[i][j][1] + bc);
        st.z = 2.f * xv.z + g * (acc[i][j][2] + bc);
        st.w = 2.f * xv.w + g * (acc[i][j][3] + bc);
        *(float4*)((float*)outp + gi) = st;
      }
    }
  }
}

// ---------- launcher ----------
extern "C" void kernel_launch(void* const* d_in, const int* in_sizes, int n_in,
                              void* d_out, int out_size, void* d_ws, size_t ws_size,
                              hipStream_t stream) {
  const void* x  = d_in[0];
  const void* Wq = d_in[1]; const void* bq = d_in[2];
  const void* Wk = d_in[3]; const void* bk = d_in[4];
  const void* Wv = d_in[5]; const void* bv = d_in[6];
  const void* Wo = d_in[7]; const void* bo = d_in[8];
  const void* gm = d_in[9];

  u16* ws = (u16*)d_ws;
  u16* xT = ws;            // scratch region; used as attn output O
  u16* Qb = ws + NT;       // (b,h,s,32), scale*log2e folded
  u16* Kb = ws + 2 * NT;   // (b,h,s,32)
  u16* Vb = ws + 3 * NT;   // (b,256,s) == (b,h,dh,s)
  u16* Ob = xT;
  const u32* xdet = (const u32*)x;

  // d_out doubles as QKV-weight scratch until out_gemm rewrites it fully
  u16* WqkvB = (u16*)d_out;                              // 3 x 65536 u16
  float* bqkvF = (float*)((u16*)d_out + 196608);         // 768 f32

  // Wo scratch: ws tail if it fits (prep folded into prologue), else dead-Q fallback
  const bool tail = ws_size >= (size_t)(4 * NT + 66048) * 2;
  u16* WoB = tail ? (ws + 4 * NT) : Qb;
  float* boF = tail ? (float*)(ws + 4 * NT + 65536) : (float*)(Qb + 65536);

  prologue_kernel<<<dim3(tail ? 256 : 192), 256, 0, stream>>>(
      x, Wq, Wk, Wv, bq, bk, bv, WqkvB, bqkvF, Wo, bo, gm, WoB, boF);
  qkv_gemm<<<dim3(8, 2, 96), 256, 0, stream>>>(x, WqkvB, bqkvF, Qb, Kb, Vb);
  attn_kernel<<<dim3(1024), 512, 0, stream>>>(Qb, Kb, Vb, Ob);
  if (!tail) prep_o<<<dim3(64), 256, 0, stream>>>(Wo, bo, gm, WoB, boF, xdet);
  out_gemm<<<dim3(8, 4, 32), 256, 0, stream>>>(WoB, boF, Ob, x, d_out, xdet);
}

// Round 10
// 186.945 us; speedup vs baseline: 1.0987x; 1.0987x over previous
//
#include <hip/hip_runtime.h>
#include <stdint.h>

typedef unsigned short u16;
typedef unsigned int   u32;
typedef __attribute__((ext_vector_type(8))) short bf16x8;  // 8 bf16 = 4 VGPR
typedef __attribute__((ext_vector_type(4))) short bf16x4;  // 4 bf16 = 2 VGPR
typedef __attribute__((ext_vector_type(4))) float f32x4;   // MFMA C/D frag
typedef __attribute__((ext_vector_type(16))) float f32x16; // 32x32 MFMA C/D frag

#define NT ((size_t)8388608)   // 32*1024*256 elements

// ---------- helpers ----------
__device__ __forceinline__ float bf2f(u16 u) {
  union { float f; u32 i; } v; v.i = ((u32)u) << 16; return v.f;
}
__device__ __forceinline__ u16 f2bf(float f) {
  union { float f; u32 i; } v; v.f = f;
  u32 r = (v.i + 0x7fffu + ((v.i >> 16) & 1u)) >> 16;   // RNE
  return (u16)r;
}
__device__ __forceinline__ u32 fbits(float f) {
  union { float f; u32 i; } v; v.f = f; return v.i;
}
// bf16-vs-f32 buffer sniff (64-lane ballot on exponent-byte position)
__device__ __forceinline__ int detect_bf16(const u32* __restrict__ xd) {
  u32 w = xd[threadIdx.x & 63];
  u32 e = (w >> 8) & 0x7fu;
  unsigned long long m = __ballot((e >= 0x38u) && (e <= 0x41u));
  return __popcll(m) > 32;
}
// async 16B/lane global->LDS (dest = wave-uniform base + lane*16)
__device__ __forceinline__ void gld16(const void* g, void* l) {
  __builtin_amdgcn_global_load_lds((const __attribute__((address_space(1))) u32*)g,
                                   (__attribute__((address_space(3))) u32*)l, 16, 0, 0);
}

// ---------- prologue: x transpose (0..2047) + Wq/Wk/Wv prep (2048..2239) + optional Wo (2240..2303) ----------
// (R9's fused-transpose qkv regressed 3x -- latency-bound serial chain at 18%
// occupancy. The separate BW-bound transpose pass is the right structure.)
__global__ void __launch_bounds__(256) prologue_kernel(const void* __restrict__ xin,
                                                       u16* __restrict__ xT,
                                                       const void* __restrict__ W0, const void* __restrict__ W1,
                                                       const void* __restrict__ W2, const void* __restrict__ b0,
                                                       const void* __restrict__ b1, const void* __restrict__ b2,
                                                       u16* __restrict__ wdst, float* __restrict__ bdst,
                                                       const void* __restrict__ Wo, const void* __restrict__ bo,
                                                       const void* __restrict__ gm, u16* __restrict__ wodst,
                                                       float* __restrict__ bodst) {
  const int blk = blockIdx.x;
  const int tid = threadIdx.x;
  const int isbf = detect_bf16((const u32*)xin);
  if (blk < 2048) {
    const int s0 = (blk & 15) * 64, c0 = ((blk >> 4) & 3) * 64, b = blk >> 6;
    __shared__ u16 T[64][72];  // [c-local][s-local], +8 pad
    if (isbf) {
      const u16* xp = (const u16*)xin;
      for (int t = tid; t < 512; t += 256) {
        int r = t >> 3, off = (t & 7) * 8;
        *(uint4*)&T[r][off] = *(const uint4*)(xp + ((size_t)(b * 256 + c0 + r)) * 1024 + s0 + off);
      }
    } else {
      const float* xp = (const float*)xin;
      for (int t = tid; t < 512; t += 256) {
        int r = t >> 3, off = (t & 7) * 8;
        const float* s = xp + ((size_t)(b * 256 + c0 + r)) * 1024 + s0 + off;
        const float4 a = *(const float4*)s;
        const float4 c = *(const float4*)(s + 4);
        T[r][off + 0] = f2bf(a.x); T[r][off + 1] = f2bf(a.y);
        T[r][off + 2] = f2bf(a.z); T[r][off + 3] = f2bf(a.w);
        T[r][off + 4] = f2bf(c.x); T[r][off + 5] = f2bf(c.y);
        T[r][off + 6] = f2bf(c.z); T[r][off + 7] = f2bf(c.w);
      }
    }
    __syncthreads();
    for (int t = tid; t < 512; t += 256) {
      int r = t >> 3, off = (t & 7) * 8;   // r = s-local, off = c-local
      union { u16 h[8]; uint4 v; } pk;
#pragma unroll
      for (int u = 0; u < 8; u++) pk.h[u] = T[off + u][r];
      *(uint4*)(xT + ((size_t)(b * 1024 + s0 + r)) * 256 + c0 + off) = pk.v;
    }
  } else if (blk < 2240) {
    const int g = blk - 2048;            // 192 blocks: 64 per weight
    const int which = g >> 6, bk = g & 63;
    const void* Ws = which == 0 ? W0 : which == 1 ? W1 : W2;
    const void* bs = which == 0 ? b0 : which == 1 ? b1 : b2;
    const int idx = bk * 1024 + tid * 4;
    u16* dst = wdst + which * 65536 + idx;
    if (isbf) {
      *(ushort4*)dst = *(const ushort4*)((const u16*)Ws + idx);
    } else {
      const float4 sv = *(const float4*)((const float*)Ws + idx);
      ushort4 o; o.x = f2bf(sv.x); o.y = f2bf(sv.y); o.z = f2bf(sv.z); o.w = f2bf(sv.w);
      *(ushort4*)dst = o;
    }
    if (bk == 0) {
      bdst[which * 256 + tid] = isbf ? bf2f(((const u16*)bs)[tid]) : ((const float*)bs)[tid];
    }
  } else {
    const int g = blk - 2240;            // 64 blocks: Wo
    const int idx = g * 1024 + tid * 4;
    if (isbf) {
      *(ushort4*)(wodst + idx) = *(const ushort4*)((const u16*)Wo + idx);
    } else {
      const float4 sv = *(const float4*)((const float*)Wo + idx);
      ushort4 o; o.x = f2bf(sv.x); o.y = f2bf(sv.y); o.z = f2bf(sv.z); o.w = f2bf(sv.w);
      *(ushort4*)(wodst + idx) = o;
    }
    if (g == 0) {
      bodst[tid] = isbf ? bf2f(((const u16*)bo)[tid]) : ((const float*)bo)[tid];
      if (tid == 0) bodst[256] = isbf ? bf2f(((const u16*)gm)[0]) : ((const float*)gm)[0];
    }
  }
}

// ---------- Wo prep fallback (when ws tail unavailable; runs after attn) ----------
__global__ void __launch_bounds__(256) prep_o(const void* __restrict__ Wo, const void* __restrict__ bo,
                                              const void* __restrict__ gm, u16* __restrict__ wdst,
                                              float* __restrict__ bdst, const u32* __restrict__ xdet) {
  const int isbf = detect_bf16(xdet);
  const int idx = blockIdx.x * 1024 + threadIdx.x * 4;
  if (isbf) {
    *(ushort4*)(wdst + idx) = *(const ushort4*)((const u16*)Wo + idx);
  } else {
    const float4 sv = *(const float4*)((const float*)Wo + idx);
    ushort4 o; o.x = f2bf(sv.x); o.y = f2bf(sv.y); o.z = f2bf(sv.z); o.w = f2bf(sv.w);
    *(ushort4*)(wdst + idx) = o;
  }
  if (blockIdx.x == 0) {
    int t = threadIdx.x;
    bdst[t] = isbf ? bf2f(((const u16*)bo)[t]) : ((const float*)bo)[t];
    if (t == 0) bdst[256] = isbf ? bf2f(((const u16*)gm)[0]) : ((const float*)gm)[0];
  }
}

// ---------- fused QKV projection, BK=64, unified orientation: D[m=c][n=s] ----------
// A = W (rows c), B = xT (rows s). Q/K head-packed ushort4 stores; V scalar.
__global__ void __launch_bounds__(256) qkv_gemm(const u16* __restrict__ xT,
                                                const u16* __restrict__ Wall,
                                                const float* __restrict__ ball,
                                                u16* __restrict__ Qb, u16* __restrict__ Kb,
                                                u16* __restrict__ Vb) {
  const int z = blockIdx.z, b = z / 3, which = z - b * 3;
  const int tid = threadIdx.x, lane = tid & 63, wave = tid >> 6;
  const int quad = lane >> 4, l16 = lane & 15;
  const int wm = wave >> 1, wn = wave & 1;
  const u16* xb = xT + (size_t)b * 262144;
  const u16* W = Wall + which * 65536;
  const int m0 = blockIdx.y * 128;   // c tile (2)
  const int n0 = blockIdx.x * 128;   // s tile (8)

  __shared__ u16 Ash[8192], Bsh[8192];   // 128 rows x 64 (128B rows), k-granule swizzled
  f32x4 acc[4][4];
#pragma unroll
  for (int i = 0; i < 4; i++)
#pragma unroll
    for (int j = 0; j < 4; j++) acc[i][j] = (f32x4){0.f, 0.f, 0.f, 0.f};

  const int srow = lane >> 3;
  const int sgc = (lane & 7) ^ (srow & 7);   // pre-swizzled source k-granule
  for (int k0 = 0; k0 < 256; k0 += 64) {
    __syncthreads();   // WAR: prior frag reads done before restage lands
#pragma unroll
    for (int p = 0; p < 4; p++) {
      const int row = p * 32 + wave * 8;
      gld16(W  + (size_t)(m0 + row + srow) * 256 + k0 + sgc * 8, &Ash[row * 64 + lane * 8]);
      gld16(xb + (size_t)(n0 + row + srow) * 256 + k0 + sgc * 8, &Bsh[row * 64 + lane * 8]);
    }
    __syncthreads();   // drains vmcnt before barrier
#pragma unroll
    for (int kk = 0; kk < 2; kk++) {
      bf16x8 av[4], bv[4];
      const int rg = (kk * 4 + quad) ^ (l16 & 7);   // swizzled read granule
#pragma unroll
      for (int i = 0; i < 4; i++) av[i] = *(const bf16x8*)&Ash[(wm * 64 + i * 16 + l16) * 64 + rg * 8];
#pragma unroll
      for (int j = 0; j < 4; j++) bv[j] = *(const bf16x8*)&Bsh[(wn * 64 + j * 16 + l16) * 64 + rg * 8];
#pragma unroll
      for (int i = 0; i < 4; i++)
#pragma unroll
        for (int j = 0; j < 4; j++)
          acc[i][j] = __builtin_amdgcn_mfma_f32_16x16x32_bf16(av[i], bv[j], acc[i][j], 0, 0, 0);
    }
  }

  const float* bias = ball + which * 256;
  const float scale = (which == 0) ? 0.25503486f : 1.0f;  // (1/sqrt(32))*log2(e) folded into Q
#pragma unroll
  for (int i = 0; i < 4; i++) {
#pragma unroll
    for (int j = 0; j < 4; j++) {
      const int mb = m0 + wm * 64 + i * 16 + quad * 4;   // c, 4-consecutive via r
      const int n = n0 + wn * 64 + j * 16 + l16;         // s
      if (which < 2) {
        u16* D = (which ? Kb : Qb) + (size_t)b * 262144;
        ushort4 st;
        st.x = f2bf((acc[i][j][0] + bias[mb + 0]) * scale);
        st.y = f2bf((acc[i][j][1] + bias[mb + 1]) * scale);
        st.z = f2bf((acc[i][j][2] + bias[mb + 2]) * scale);
        st.w = f2bf((acc[i][j][3] + bias[mb + 3]) * scale);
        // head-packed (h, s, dh); mb%4==0 so the quad stays inside one head
        *(ushort4*)(D + (size_t)(mb >> 5) * 32768 + (size_t)n * 32 + (mb & 31)) = st;
      } else {
        u16* D = Vb + (size_t)b * 262144;
#pragma unroll
        for (int r = 0; r < 4; r++) {
          const int m = mb + r;
          D[(size_t)m * 1024 + n] = f2bf(acc[i][j][r] + bias[m]);
        }
      }
    }
  }
}

// ---------- fused attention (best measured: 53.1us, unchanged) ----------
__global__ void __launch_bounds__(512) attn_kernel(const u16* __restrict__ Q,
                                                   const u16* __restrict__ K,
                                                   const u16* __restrict__ V,
                                                   u16* __restrict__ O) {
  const int blk = blockIdx.x;
  const int qc = blk >> 8, bh = blk & 255;
  const int b = bh >> 3, h = bh & 7;
  const int tid = threadIdx.x, wave = tid >> 6, lane = tid & 63;
  const int hi = lane >> 5, l32 = lane & 31;
  __shared__ __align__(16) u16 Ksh[2][128 * 32];  // [t][d] granule-swizzled
  __shared__ __align__(16) u16 Vsh[2][32 * 128];  // [d][t] granule col ^= (d&15)
  const u16* Qg = Q + (size_t)b * 262144 + (size_t)h * 32768;  // (b,h,s,32)
  const u16* Kg = K + (size_t)b * 262144 + (size_t)h * 32768;  // (b,h,s,32)
  const u16* Vg = V + (size_t)b * 262144 + (size_t)h * 32768;  // (b,h,dh,s)
  const int qw = qc * 256 + wave * 32;   // this wave's 32 q rows

  // Q frags (B-operand): lane n=l32 holds Q[q=qw+l32][d = ks*16 + hi*8 + j]
  bf16x8 qf[2];
#pragma unroll
  for (int ks = 0; ks < 2; ks++)
    qf[ks] = *(const bf16x8*)(Qg + (size_t)(qw + l32) * 32 + ks * 16 + hi * 8);

  // K staging: this lane's granule Gg; location Gg must hold K[t(Gg)][8*s(Gg)..+7]
  const int Gg = wave * 64 + lane;
  const int th = Gg >> 3;
  const int uu = (Gg & 7) ^ (th & 7);
  const u16* ksrc = Kg + (size_t)(th * 2 + (uu >> 2)) * 32 + (uu & 3) * 8;
  u16* kdst0 = &Ksh[0][Gg * 8];
  u16* kdst1 = &Ksh[1][Gg * 8];
  // V staging: granule tid holds V[d = tid>>4][8*((tid&15)^(d&15)) ..+7]
  const int vd = tid >> 4;
  const u16* vsrc = Vg + (size_t)vd * 1024 + ((tid & 15) ^ (vd & 15)) * 8;
  u16* vdst0 = &Vsh[0][tid * 8];
  u16* vdst1 = &Vsh[1][tid * 8];

  // kf read byte-offsets (A-operand, lane m = t = tt*32+l32, k-half ks): +tt*2048
  const int kkey = (l32 >> 1) & 7;
  const int kb0 = (l32 >> 1) * 128 + (((((l32 & 1) << 2) | 0 | hi) ^ kkey) << 4);
  const int kb1 = (l32 >> 1) * 128 + (((((l32 & 1) << 2) | 2 | hi) ^ kkey) << 4);
  // vf read byte-offsets: l32*256 + ((tg ^ (l32&15))<<4), tg = 4*tt + 2*m + hi
  int vb[4];
#pragma unroll
  for (int tt = 0; tt < 4; tt++) vb[tt] = l32 * 256 + (((l32 & 12) ^ (tt << 2)) << 4);
  const int vm0 = ((l32 & 3) ^ hi) << 4;
  const int vm1 = ((l32 & 3) ^ (2 | hi)) << 4;

  f32x16 oacc;
#pragma unroll
  for (int r = 0; r < 16; r++) oacc[r] = 0.f;
  f32x16 zro;   // persistent zero C-operand for QK^T (never written)
#pragma unroll
  for (int r = 0; r < 16; r++) zro[r] = 0.f;
  float lsum = 0.f;

  // prologue: stage tile 0
  gld16(ksrc, kdst0);
  gld16(vsrc, vdst0);
  __syncthreads();

#pragma unroll 1
  for (int kt = 0; kt < 8; kt++) {
    const int c = kt & 1;
    if (kt < 7) {   // issue next tile into the other buffer; drained at loop-end barrier
      gld16(ksrc + (size_t)(kt + 1) * 4096, c ? kdst0 : kdst1);   // 128 t-rows x 32
      gld16(vsrc + (kt + 1) * 128,          c ? vdst0 : vdst1);
    }
    const char* Kb = (const char*)&Ksh[c][0];
    const char* Vb = (const char*)&Vsh[c][0];
#pragma unroll
    for (int tt = 0; tt < 4; tt++) {
      const bf16x8 kf0 = *(const bf16x8*)(Kb + tt * 2048 + kb0);
      const bf16x8 kf1 = *(const bf16x8*)(Kb + tt * 2048 + kb1);
      const bf16x8 vf0 = *(const bf16x8*)(Vb + vb[tt] + vm0);
      const bf16x8 vf1 = *(const bf16x8*)(Vb + vb[tt] + vm1);
      __builtin_amdgcn_s_setprio(1);
      f32x16 sf = __builtin_amdgcn_mfma_f32_32x32x16_bf16(kf0, qf[0], zro, 0, 0, 0);
      sf = __builtin_amdgcn_mfma_f32_32x32x16_bf16(kf1, qf[1], sf, 0, 0, 0);
      __builtin_amdgcn_s_setprio(0);
      // ---- first 16 t of the tile (groups g0 = sf[0:3], g1 = sf[4:7]) ----
      {
        const float p0 = __builtin_amdgcn_exp2f(sf[0]);
        const float p1 = __builtin_amdgcn_exp2f(sf[1]);
        const float p2 = __builtin_amdgcn_exp2f(sf[2]);
        const float p3 = __builtin_amdgcn_exp2f(sf[3]);
        const float p4 = __builtin_amdgcn_exp2f(sf[4]);
        const float p5 = __builtin_amdgcn_exp2f(sf[5]);
        const float p6 = __builtin_amdgcn_exp2f(sf[6]);
        const float p7 = __builtin_amdgcn_exp2f(sf[7]);
        lsum += ((p0 + p1) + (p2 + p3)) + ((p4 + p5) + (p6 + p7));
        u32 wa, wb, wc, wd;
        asm("v_cvt_pk_bf16_f32 %0, %1, %2" : "=v"(wa) : "v"(p0), "v"(p1));
        asm("v_cvt_pk_bf16_f32 %0, %1, %2" : "=v"(wb) : "v"(p2), "v"(p3));
        asm("v_cvt_pk_bf16_f32 %0, %1, %2" : "=v"(wc) : "v"(p4), "v"(p5));
        asm("v_cvt_pk_bf16_f32 %0, %1, %2" : "=v"(wd) : "v"(p6), "v"(p7));
#if __has_builtin(__builtin_amdgcn_permlane32_swap)
        auto s0 = __builtin_amdgcn_permlane32_swap((int)wc, (int)wa, false, false);
        auto s1 = __builtin_amdgcn_permlane32_swap((int)wd, (int)wb, false, false);
        union { int w[4]; bf16x8 v; } pk;
        pk.w[0] = s0[1]; pk.w[1] = s1[1]; pk.w[2] = s0[0]; pk.w[3] = s1[0];
#else
        const u32 xa = __shfl_xor((int)wa, 32), xb = __shfl_xor((int)wb, 32);
        const u32 xc = __shfl_xor((int)wc, 32), xd = __shfl_xor((int)wd, 32);
        union { u32 w[4]; bf16x8 v; } pk;
        pk.w[0] = hi ? xc : wa; pk.w[1] = hi ? xd : wb;
        pk.w[2] = hi ? wc : xa; pk.w[3] = hi ? wd : xb;
#endif
        __builtin_amdgcn_s_setprio(1);
        oacc = __builtin_amdgcn_mfma_f32_32x32x16_bf16(pk.v, vf0, oacc, 0, 0, 0);
        __builtin_amdgcn_s_setprio(0);
      }
      // ---- second 16 t of the tile (groups g2 = sf[8:11], g3 = sf[12:15]) ----
      {
        const float p0 = __builtin_amdgcn_exp2f(sf[8]);
        const float p1 = __builtin_amdgcn_exp2f(sf[9]);
        const float p2 = __builtin_amdgcn_exp2f(sf[10]);
        const float p3 = __builtin_amdgcn_exp2f(sf[11]);
        const float p4 = __builtin_amdgcn_exp2f(sf[12]);
        const float p5 = __builtin_amdgcn_exp2f(sf[13]);
        const float p6 = __builtin_amdgcn_exp2f(sf[14]);
        const float p7 = __builtin_amdgcn_exp2f(sf[15]);
        lsum += ((p0 + p1) + (p2 + p3)) + ((p4 + p5) + (p6 + p7));
        u32 wa, wb, wc, wd;
        asm("v_cvt_pk_bf16_f32 %0, %1, %2" : "=v"(wa) : "v"(p0), "v"(p1));
        asm("v_cvt_pk_bf16_f32 %0, %1, %2" : "=v"(wb) : "v"(p2), "v"(p3));
        asm("v_cvt_pk_bf16_f32 %0, %1, %2" : "=v"(wc) : "v"(p4), "v"(p5));
        asm("v_cvt_pk_bf16_f32 %0, %1, %2" : "=v"(wd) : "v"(p6), "v"(p7));
#if __has_builtin(__builtin_amdgcn_permlane32_swap)
        auto s0 = __builtin_amdgcn_permlane32_swap((int)wc, (int)wa, false, false);
        auto s1 = __builtin_amdgcn_permlane32_swap((int)wd, (int)wb, false, false);
        union { int w[4]; bf16x8 v; } pk;
        pk.w[0] = s0[1]; pk.w[1] = s1[1]; pk.w[2] = s0[0]; pk.w[3] = s1[0];
#else
        const u32 xa = __shfl_xor((int)wa, 32), xb = __shfl_xor((int)wb, 32);
        const u32 xc = __shfl_xor((int)wc, 32), xd = __shfl_xor((int)wd, 32);
        union { u32 w[4]; bf16x8 v; } pk;
        pk.w[0] = hi ? xc : wa; pk.w[1] = hi ? xd : wb;
        pk.w[2] = hi ? wc : xa; pk.w[3] = hi ? wd : xb;
#endif
        __builtin_amdgcn_s_setprio(1);
        oacc = __builtin_amdgcn_mfma_f32_32x32x16_bf16(pk.v, vf1, oacc, 0, 0, 0);
        __builtin_amdgcn_s_setprio(0);
      }
    }
    if (kt < 7) __syncthreads();   // drains vmcnt (prefetch) + WAR for restage
  }

  // epilogue: row-sums (lane + its hi-partner), scale, store
  lsum += __shfl_xor(lsum, 32);
  const float linv = 1.0f / lsum;            // valid at lane for q = l32
  u16* Og = O + (size_t)(b * 1024 + qw) * 256 + h * 32 + l32;
#pragma unroll
  for (int r = 0; r < 16; r++) {
    const int qo = (r & 3) + 8 * (r >> 2) + 4 * hi;   // oacc row -> q offset
    const float li = __shfl(linv, qo);
    Og[(size_t)qo * 256] = f2bf(oacc[r] * li);
  }
}

// ---------- out projection + residual v4: DOUBLE-BUFFERED (attn's pattern) ----------
// R9 showed these small GEMMs are barrier-latency-bound (2 syncs/K-step, zero
// prefetch overlap). Convert to attn's proven dbuf: stage k0=0, then per k:
// issue k+1's gld16 into the other buffer BEFORE the MFMAs, ONE barrier/iter.
// LDS 24->48KB (3 blocks/CU vs 4) -- the same trade attn makes, wins when
// latency not occupancy binds. D[m=s][n=c]; float4 x-loads/stores.
__global__ void __launch_bounds__(256) out_gemm(const u16* __restrict__ WoB,
                                                const float* __restrict__ bg,
                                                const u16* __restrict__ Ob,
                                                const void* __restrict__ xin,
                                                void* __restrict__ outp,
                                                const u32* __restrict__ xdet) {
  const int b = blockIdx.z;
  const int m0 = blockIdx.x * 128;   // s tile (8)
  const int n0 = blockIdx.y * 64;    // c tile (4)
  const int tid = threadIdx.x, lane = tid & 63, wave = tid >> 6;
  const int quad = lane >> 4, l16 = lane & 15;
  const int wm = wave >> 1, wn = wave & 1;   // per wave: 64 m x 32 n
  const int isbf = detect_bf16(xdet);
  const u16* Ab = Ob + (size_t)b * 262144;   // A rows = s (k-major 256)
  __shared__ u16 Ash[2][8192], Bsh[2][4096]; // dbuf: A 128x64, B 64x64 (swizzled)
  f32x4 acc[4][2];
#pragma unroll
  for (int i = 0; i < 4; i++)
#pragma unroll
    for (int j = 0; j < 2; j++) acc[i][j] = (f32x4){0.f, 0.f, 0.f, 0.f};

  const int srow = lane >> 3;
  const int sgc = (lane & 7) ^ (srow & 7);   // pre-swizzled source k-granule

  // prologue: stage k0=0 into buffer 0
#pragma unroll
  for (int p = 0; p < 4; p++) {
    const int row = p * 32 + wave * 8;
    gld16(Ab + (size_t)(m0 + row + srow) * 256 + sgc * 8, &Ash[0][row * 64 + lane * 8]);
  }
#pragma unroll
  for (int p = 0; p < 2; p++) {
    const int row = p * 32 + wave * 8;
    gld16(WoB + (size_t)(n0 + row + srow) * 256 + sgc * 8, &Bsh[0][row * 64 + lane * 8]);
  }
  __syncthreads();   // drains prologue stage

#pragma unroll
  for (int k = 0; k < 4; k++) {
    const int c = k & 1;
    if (k < 3) {   // issue next K-step into the other buffer; latency hidden under MFMAs
      const int k0 = (k + 1) * 64;
#pragma unroll
      for (int p = 0; p < 4; p++) {
        const int row = p * 32 + wave * 8;
        gld16(Ab + (size_t)(m0 + row + srow) * 256 + k0 + sgc * 8, &Ash[c ^ 1][row * 64 + lane * 8]);
      }
#pragma unroll
      for (int p = 0; p < 2; p++) {
        const int row = p * 32 + wave * 8;
        gld16(WoB + (size_t)(n0 + row + srow) * 256 + k0 + sgc * 8, &Bsh[c ^ 1][row * 64 + lane * 8]);
      }
    }
#pragma unroll
    for (int kk = 0; kk < 2; kk++) {
      bf16x8 av[4], bv[2];
      const int rg = (kk * 4 + quad) ^ (l16 & 7);   // swizzled read granule
#pragma unroll
      for (int i = 0; i < 4; i++) av[i] = *(const bf16x8*)&Ash[c][(wm * 64 + i * 16 + l16) * 64 + rg * 8];
#pragma unroll
      for (int j = 0; j < 2; j++) bv[j] = *(const bf16x8*)&Bsh[c][(wn * 32 + j * 16 + l16) * 64 + rg * 8];
#pragma unroll
      for (int i = 0; i < 4; i++)
#pragma unroll
        for (int j = 0; j < 2; j++)
          acc[i][j] = __builtin_amdgcn_mfma_f32_16x16x32_bf16(av[i], bv[j], acc[i][j], 0, 0, 0);
    }
    if (k < 3) __syncthreads();   // drains prefetch (vmcnt) + WAR for next restage
  }

  const float g = bg[256];
#pragma unroll
  for (int i = 0; i < 4; i++) {
#pragma unroll
    for (int j = 0; j < 2; j++) {
      const int mb = m0 + wm * 64 + i * 16 + quad * 4;   // s, 4-consecutive via r
      const int n = n0 + wn * 32 + j * 16 + l16;         // c
      const float bc = bg[n];
      const size_t gi = (size_t)b * 262144 + (size_t)n * 1024 + mb;
      if (isbf) {
        const ushort4 xv = *(const ushort4*)((const u16*)xin + gi);
        ushort4 st;
        st.x = f2bf(2.f * bf2f(xv.x) + g * (acc[i][j][0] + bc));
        st.y = f2bf(2.f * bf2f(xv.y) + g * (acc[i][j][1] + bc));
        st.z = f2bf(2.f * bf2f(xv.z) + g * (acc[i][j][2] + bc));
        st.w = f2bf(2.f * bf2f(xv.w) + g * (acc[i][j][3] + bc));
        *(ushort4*)((u16*)outp + gi) = st;
      } else {
        const float4 xv = *(const float4*)((const float*)xin + gi);
        float4 st;
        st.x = 2.f * xv.x + g * (acc[i][j][0] + bc);
        st.y = 2.f * xv.y + g * (acc[i][j][1] + bc);
        st.z = 2.f * xv.z + g * (acc[i][j][2] + bc);
        st.w = 2.f * xv.w + g * (acc[i][j][3] + bc);
        *(float4*)((float*)outp + gi) = st;
      }
    }
  }
}

// ---------- launcher ----------
extern "C" void kernel_launch(void* const* d_in, const int* in_sizes, int n_in,
                              void* d_out, int out_size, void* d_ws, size_t ws_size,
                              hipStream_t stream) {
  const void* x  = d_in[0];
  const void* Wq = d_in[1]; const void* bq = d_in[2];
  const void* Wk = d_in[3]; const void* bk = d_in[4];
  const void* Wv = d_in[5]; const void* bv = d_in[6];
  const void* Wo = d_in[7]; const void* bo = d_in[8];
  const void* gm = d_in[9];

  u16* ws = (u16*)d_ws;
  u16* xT = ws;            // (b,s,c) bf16; reused as O after V-proj
  u16* Qb = ws + NT;       // (b,h,s,32), scale*log2e folded
  u16* Kb = ws + 2 * NT;   // (b,h,s,32)
  u16* Vb = ws + 3 * NT;   // (b,256,s) == (b,h,dh,s)
  u16* Ob = xT;
  const u32* xdet = (const u32*)x;

  // d_out doubles as QKV-weight scratch until out_gemm rewrites it fully
  u16* WqkvB = (u16*)d_out;                              // 3 x 65536 u16
  float* bqkvF = (float*)((u16*)d_out + 196608);         // 768 f32

  // Wo scratch: ws tail if it fits (prep folded into prologue), else dead-Q fallback
  const bool tail = ws_size >= (size_t)(4 * NT + 66048) * 2;
  u16* WoB = tail ? (ws + 4 * NT) : Qb;
  float* boF = tail ? (float*)(ws + 4 * NT + 65536) : (float*)(Qb + 65536);

  prologue_kernel<<<dim3(tail ? 2304 : 2240), 256, 0, stream>>>(
      x, xT, Wq, Wk, Wv, bq, bk, bv, WqkvB, bqkvF, Wo, bo, gm, WoB, boF);
  qkv_gemm<<<dim3(8, 2, 96), 256, 0, stream>>>(xT, WqkvB, bqkvF, Qb, Kb, Vb);
  attn_kernel<<<dim3(1024), 512, 0, stream>>>(Qb, Kb, Vb, Ob);
  if (!tail) prep_o<<<dim3(64), 256, 0, stream>>>(Wo, bo, gm, WoB, boF, xdet);
  out_gemm<<<dim3(8, 4, 32), 256, 0, stream>>>(WoB, boF, Ob, x, d_out, xdet);
}